// Round 2
// baseline (199.514 us; speedup 1.0000x reference)
//
#include <hip/hip_runtime.h>
#include <math.h>

#define NB 256     // N nodes
#define CH 64      // C input features
#define OUTF 64    // O output features
#define GK 8       // GRID_SIZE + SPLINE_ORDER
#define UIN (CH + OUTF)  // 128 update-KAN input dim

__device__ __forceinline__ float silu(float v) {
    return v * __builtin_amdgcn_rcpf(1.0f + __expf(-v));
}

// Uniform cubic B-spline, knots t(m) = 0.4*m - 2.2 (m=0..11), 8 basis funcs.
// Only 4 bases nonzero for r in interval d: m = d-3..d with segment values
// {(1-u)^3, 3u^3-6u^2+4, -3u^3+3u^2+3u+1, u^3}/6.  Out of grid -> d=12
// (so padded-table reads d..d+3 hit zeros, and (unsigned)(d-3+k)<8 is false).
__device__ __forceinline__ void spline4(float r, int& d, float4& v) {
    float p = (r + 2.2f) * 2.5f;
    float fd = floorf(p);
    d = (int)fd;
    float u = p - fd;
    if ((unsigned)d > 10u) d = 12;
    float um = 1.0f - u;
    float u2 = u * u;
    float u3 = u2 * u;
    const float k6 = 1.0f / 6.0f;
    v.x = um * um * um * k6;                          // m = d-3
    v.y = (3.0f * u3 - 6.0f * u2 + 4.0f) * k6;        // m = d-2
    v.z = (-3.0f * u3 + 3.0f * u2 + 3.0f * u + 1.0f) * k6; // m = d-1
    v.w = u3 * k6;                                    // m = d
}

// msg[row, o] = kan_linear(x[row,:], mw_*)   — one block per row, 256 thr
__global__ __launch_bounds__(256) void msg_kernel(
    const float* __restrict__ x,
    const float* __restrict__ mwb,   // (O, C)
    const float* __restrict__ mws,   // (O, C, GK)
    const float* __restrict__ mwsc,  // (O, C)
    float* __restrict__ msg) {
    const int row = blockIdx.x;
    const int tid = threadIdx.x;

    __shared__ float ssil[CH];
    __shared__ int sd[CH];
    __shared__ float4 sv[CH];
    __shared__ float part[4][OUTF];

    if (tid < CH) {
        float v = x[row * CH + tid];
        ssil[tid] = silu(v);
        int d; float4 vv; spline4(v, d, vv);
        sd[tid] = d; sv[tid] = vv;
    }
    __syncthreads();

    const int o = tid & 63, seg = tid >> 6;
    float acc = 0.0f;
#pragma unroll
    for (int cc = 0; cc < 16; ++cc) {
        int c = seg * 16 + cc;
        int d = sd[c];
        float4 vv = sv[c];
        const float* wp = mws + (o * CH + c) * GK;
        float s = 0.0f;
#pragma unroll
        for (int k = 0; k < 4; ++k) {
            int m = d - 3 + k;
            float w = ((unsigned)m < 8u) ? wp[m] : 0.0f;
            s += ((const float*)&vv)[k] * w;
        }
        acc += s * mwsc[o * CH + c] + ssil[c] * mwb[o * CH + c];
    }
    part[seg][o] = acc;
    __syncthreads();
    if (tid < OUTF)
        msg[row * OUTF + tid] = part[0][tid] + part[1][tid] + part[2][tid] + part[3][tid];
}

// One block per (b,i): energy(i,*) -> softmax -> aggregate -> update-KAN
__global__ __launch_bounds__(256) void gat_kernel(
    const float* __restrict__ x,
    const int* __restrict__ adj,
    const float* __restrict__ fwb,   // (1, C)
    const float* __restrict__ fws,   // (1, C, GK)
    const float* __restrict__ fwsc,  // (1, C)
    const float* __restrict__ uwb,   // (O, UIN)
    const float* __restrict__ uws,   // (O, UIN, GK)
    const float* __restrict__ uwsc,  // (O, UIN)
    const float* __restrict__ msg,   // (B, N, O)
    float* __restrict__ out) {
    const int b = blockIdx.x >> 8;
    const int i = blockIdx.x & 255;
    const int tid = threadIdx.x;   // == j in energy phase

    __shared__ float xi[CH];
    __shared__ float sfb[CH];
    __shared__ float wpad[CH][16];   // fw_spline*fw_scaler, zero-padded: e=m+3
    __shared__ float alpha[NB];
    __shared__ float comb[UIN];
    __shared__ float part[4][OUTF];
    __shared__ float usil[UIN];
    __shared__ int usd[UIN];
    __shared__ float4 usv[UIN];
    __shared__ float wred[4];

    if (tid < CH) {
        float v = x[(b * NB + i) * CH + tid];
        xi[tid] = v;
        comb[tid] = v;
        sfb[tid] = fwb[tid];
        float sc = fwsc[tid];
#pragma unroll
        for (int e = 0; e < 16; ++e) {
            int m = e - 3;
            wpad[tid][e] = ((unsigned)m < 8u) ? fws[tid * GK + m] * sc : 0.0f;
        }
    }
    __syncthreads();

    // ---- energy(i, j=tid): load xj as float4, consume immediately ----
    const float4* xjp = (const float4*)(x + (b * NB + tid) * CH);
    float e = 0.0f;
#pragma unroll
    for (int q = 0; q < 16; ++q) {
        float4 xv = xjp[q];
#pragma unroll
        for (int t = 0; t < 4; ++t) {
            int c = q * 4 + t;
            float r = xi[c] - ((const float*)&xv)[t];
            int d; float4 vv; spline4(r, d, vv);
            float s = vv.x * wpad[c][d] + vv.y * wpad[c][d + 1]
                    + vv.z * wpad[c][d + 2] + vv.w * wpad[c][d + 3];
            e += s + silu(r) * sfb[c];
        }
    }
    if (adj[(b * NB + i) * NB + tid] == 0) e = -1e9f;

    // ---- softmax over j (wave shuffle + 4-entry LDS) ----
    float mx = e;
#pragma unroll
    for (int off = 32; off > 0; off >>= 1)
        mx = fmaxf(mx, __shfl_xor(mx, off, 64));
    if ((tid & 63) == 0) wred[tid >> 6] = mx;
    __syncthreads();
    mx = fmaxf(fmaxf(wred[0], wred[1]), fmaxf(wred[2], wred[3]));
    float pexp = __expf(e - mx);
    float sw = pexp;
#pragma unroll
    for (int off = 32; off > 0; off >>= 1)
        sw += __shfl_xor(sw, off, 64);
    __syncthreads();           // everyone done reading wred (max)
    if ((tid & 63) == 0) wred[tid >> 6] = sw;
    __syncthreads();
    float denom = wred[0] + wred[1] + wred[2] + wred[3];
    alpha[tid] = pexp * __builtin_amdgcn_rcpf(denom);
    __syncthreads();

    // ---- aggr[o] = sum_j alpha[j]*msg[b,j,o] ----
    {
        const int o = tid & 63, seg = tid >> 6;
        const float* msgb = msg + (b * NB + seg * 64) * OUTF;
        float a = 0.0f;
#pragma unroll 8
        for (int jj = 0; jj < 64; ++jj)
            a += alpha[seg * 64 + jj] * msgb[jj * OUTF + o];
        part[seg][o] = a;
    }
    __syncthreads();
    if (tid < OUTF)
        comb[CH + tid] = part[0][tid] + part[1][tid] + part[2][tid] + part[3][tid];
    __syncthreads();

    // ---- update-KAN activations (128 channels) ----
    if (tid < UIN) {
        float v = comb[tid];
        usil[tid] = silu(v);
        int d; float4 vv; spline4(v, d, vv);
        usd[tid] = d; usv[tid] = vv;
    }
    __syncthreads();

    // ---- update-KAN matvec: thread (o, seg) covers 32 channels ----
    {
        const int o = tid & 63, seg = tid >> 6;
        float acc = 0.0f;
#pragma unroll
        for (int cc = 0; cc < 32; ++cc) {
            int c = seg * 32 + cc;
            int d = usd[c];
            float4 vv = usv[c];
            const float* wp = uws + (o * UIN + c) * GK;
            float s = 0.0f;
#pragma unroll
            for (int k = 0; k < 4; ++k) {
                int m = d - 3 + k;
                float w = ((unsigned)m < 8u) ? wp[m] : 0.0f;
                s += ((const float*)&vv)[k] * w;
            }
            acc += s * uwsc[o * UIN + c] + usil[c] * uwb[o * UIN + c];
        }
        part[seg][o] = acc;
    }
    __syncthreads();
    if (tid < OUTF)
        out[(b * NB + i) * OUTF + tid] =
            part[0][tid] + part[1][tid] + part[2][tid] + part[3][tid];
}

extern "C" void kernel_launch(void* const* d_in, const int* in_sizes, int n_in,
                              void* d_out, int out_size, void* d_ws, size_t ws_size,
                              hipStream_t stream) {
    const float* x     = (const float*)d_in[0];
    const int*   adj   = (const int*)d_in[1];
    const float* fwb   = (const float*)d_in[2];
    const float* fws   = (const float*)d_in[3];
    const float* fwsc  = (const float*)d_in[4];
    const float* mwb   = (const float*)d_in[5];
    const float* mws   = (const float*)d_in[6];
    const float* mwsc  = (const float*)d_in[7];
    const float* uwb   = (const float*)d_in[8];
    const float* uws   = (const float*)d_in[9];
    const float* uwsc  = (const float*)d_in[10];
    float* out = (float*)d_out;

    const int BN = in_sizes[0] / CH;   // B * N = 512
    float* msg = (float*)d_ws;         // BN * OUTF floats

    msg_kernel<<<BN, 256, 0, stream>>>(x, mwb, mws, mwsc, msg);
    gat_kernel<<<BN, 256, 0, stream>>>(x, adj, fwb, fws, fwsc,
                                       uwb, uws, uwsc, msg, out);
}

// Round 3
// 99.974 us; speedup vs baseline: 1.9957x; 1.9957x over previous
//
#include <hip/hip_runtime.h>
#include <math.h>

#define NB 256     // N nodes
#define CH 64      // C input features
#define OUTF 64    // O output features
#define GK 8       // GRID_SIZE + SPLINE_ORDER
#define UIN 128    // update-KAN input dim (C + O)
#define KM (CH * 9)    // 576 feature rows for msg KAN (8 spline + 1 silu per ch)
#define KM4 (KM / 4)   // 144
#define KU (UIN * 9)   // 1152 feature rows for update KAN
#define KU4 (KU / 4)   // 288

// workspace layout in floats
#define WS_MSG 0                     // 512*64            = 32768
#define WS_XT 32768                  // 2*64*256          = 32768
#define WS_W2M 65536                 // 144*64*4          = 36864
#define WS_W2U 102400                // 288*64*4          = 73728
// total 176128 floats = 688 KB

__device__ __forceinline__ float silu(float v) {
    return v * __builtin_amdgcn_rcpf(1.0f + __expf(-v));
}

// Uniform cubic B-spline, knots t(m)=0.4m-2.2. Interval d=floor((r+2.2)*2.5),
// u=frac. 4 nonzero bases m=d-3..d with segment polys
// {(1-u)^3, 3u^3-6u^2+4, -3u^3+3u^2+3u+1, u^3}/6. Out of grid -> d=11 (zeros).
__device__ __forceinline__ void spline4(float r, int& d, float4& v) {
    float p = (r + 2.2f) * 2.5f;
    float fd = floorf(p);
    d = (int)fd;
    float u = p - fd;
    if ((unsigned)d > 10u) d = 11;
    float um = 1.0f - u;
    float u2 = u * u, u3 = u2 * u;
    const float k6 = 1.0f / 6.0f;
    v.x = um * um * um * k6;
    v.y = (3.0f * u3 - 6.0f * u2 + 4.0f) * k6;
    v.z = (-3.0f * u3 + 3.0f * u2 + 3.0f * u + 1.0f) * k6;
    v.w = u3 * k6;
}

// One-time data layout prep: xT transpose + folded/transposed weight tables.
__global__ __launch_bounds__(256) void prep_kernel(
    const float* __restrict__ x,
    const float* __restrict__ mwb, const float* __restrict__ mws,
    const float* __restrict__ mwsc,
    const float* __restrict__ uwb, const float* __restrict__ uws,
    const float* __restrict__ uwsc,
    float* __restrict__ ws) {
    int t = blockIdx.x * 256 + threadIdx.x;
    if (t < 2 * NB * CH) {                       // xT[b][c][j] = x[b][j][c]
        int b = t >> 14, rem = t & 16383, j = rem >> 6, c = rem & 63;
        ws[WS_XT + b * CH * NB + c * NB + j] = x[t];
        return;
    }
    int t2 = t - 2 * NB * CH;
    if (t2 < KM4 * OUTF) {                       // W2m[k4][o] float4 over k
        int k4 = t2 >> 6, o = t2 & 63;
        float4 v;
#pragma unroll
        for (int kk = 0; kk < 4; ++kk) {
            int k = k4 * 4 + kk, c = k / 9, g = k - c * 9;
            ((float*)&v)[kk] = (g < 8)
                ? mws[(o * CH + c) * GK + g] * mwsc[o * CH + c]
                : mwb[o * CH + c];
        }
        ((float4*)(ws + WS_W2M))[t2] = v;
        return;
    }
    int t3 = t2 - KM4 * OUTF;
    if (t3 < KU4 * OUTF) {                       // W2u[k4][o] float4 over k
        int k4 = t3 >> 6, o = t3 & 63;
        float4 v;
#pragma unroll
        for (int kk = 0; kk < 4; ++kk) {
            int k = k4 * 4 + kk, c = k / 9, g = k - c * 9;
            ((float*)&v)[kk] = (g < 8)
                ? uws[(o * UIN + c) * GK + g] * uwsc[o * UIN + c]
                : uwb[o * UIN + c];
        }
        ((float4*)(ws + WS_W2U))[t3] = v;
    }
}

// msg[row,o]: features in LDS, then 4 waves x 36 float4-k iters, coalesced W.
__global__ __launch_bounds__(256) void msg_kernel(
    const float* __restrict__ x, const float* __restrict__ w2m,
    float* __restrict__ msg) {
    const int row = blockIdx.x, tid = threadIdx.x;
    __shared__ __align__(16) float F[KM];
    __shared__ float part[4][OUTF];

    if (tid < CH) {
        float v = x[row * CH + tid];
#pragma unroll
        for (int g = 0; g < 8; ++g) F[tid * 9 + g] = 0.0f;
        F[tid * 9 + 8] = silu(v);
        int d; float4 vv; spline4(v, d, vv);
#pragma unroll
        for (int k = 0; k < 4; ++k) {
            int m = d - 3 + k;
            if ((unsigned)m < 8u) F[tid * 9 + m] = ((const float*)&vv)[k];
        }
    }
    __syncthreads();

    const int o = tid & 63, w = tid >> 6;
    const float4* W = (const float4*)w2m;
    const float4* Fv = (const float4*)F;
    float acc = 0.0f;
#pragma unroll 4
    for (int k4 = w * 36; k4 < w * 36 + 36; ++k4) {
        float4 f = Fv[k4];                 // uniform LDS b128 broadcast
        float4 wt = W[k4 * 64 + o];        // coalesced 1KB/wave
        acc += f.x * wt.x + f.y * wt.y + f.z * wt.z + f.w * wt.w;
    }
    part[w][o] = acc;
    __syncthreads();
    if (tid < OUTF)
        msg[row * OUTF + tid] =
            part[0][tid] + part[1][tid] + part[2][tid] + part[3][tid];
}

// One block per (b,i): energy -> softmax -> aggregate -> update KAN.
__global__ __launch_bounds__(256) void gat_kernel(
    const float* __restrict__ xT,    // (B, C, N) transposed
    const float* __restrict__ x,     // (B, N, C) original (row i load)
    const int* __restrict__ adj,
    const float* __restrict__ fwb, const float* __restrict__ fws,
    const float* __restrict__ fwsc,
    const float* __restrict__ w2u,   // (KU4*64) float4
    const float* __restrict__ msg,   // (B, N, O)
    float* __restrict__ out) {
    const int b = blockIdx.x >> 8;
    const int i = blockIdx.x & 255;
    const int tid = threadIdx.x;     // == j in energy phase

    __shared__ float4 cpad[CH][16];  // per-interval cubic coefs (zero-padded)
    __shared__ float2 xisf[CH];      // {xi[c], fwb[c]}
    __shared__ float alpha[NB];
    __shared__ float comb[UIN];
    __shared__ __align__(16) float Fu[KU];
    __shared__ float part[4][OUTF];
    __shared__ float wred[4];

    if (tid < CH) {
        float v = x[(b * NB + i) * CH + tid];
        xisf[tid] = make_float2(v, fwb[tid]);
        comb[tid] = v;
    }
    // cubic coefficient table: s(u) = a0 + u(a1 + u(a2 + u a3)) on interval d
#pragma unroll
    for (int e = tid; e < CH * 16; e += 256) {
        int c = e >> 4, dd = e & 15;
        float4 cf = make_float4(0.f, 0.f, 0.f, 0.f);
        if (dd <= 10) {
            float sc = fwsc[c];
            float w0 = 0.f, w1 = 0.f, w2 = 0.f, w3 = 0.f;
            int m0 = dd - 3;
            if ((unsigned)(m0 + 0) < 8u) w0 = fws[c * GK + m0 + 0] * sc;
            if ((unsigned)(m0 + 1) < 8u) w1 = fws[c * GK + m0 + 1] * sc;
            if ((unsigned)(m0 + 2) < 8u) w2 = fws[c * GK + m0 + 2] * sc;
            if ((unsigned)(m0 + 3) < 8u) w3 = fws[c * GK + m0 + 3] * sc;
            cf.x = (w0 + 4.0f * w1 + w2) * (1.0f / 6.0f);
            cf.y = (w2 - w0) * 0.5f;
            cf.z = (w0 - 2.0f * w1 + w2) * 0.5f;
            cf.w = (w3 - w0 + 3.0f * (w1 - w2)) * (1.0f / 6.0f);
        }
        cpad[c][dd] = cf;
    }
    __syncthreads();

    // ---- energy(i, j=tid): coalesced xT loads + LDS b128 coef gather ----
    const float* xTb = xT + b * CH * NB;
    float e = 0.0f;
#pragma unroll 4
    for (int c = 0; c < CH; ++c) {
        float xj = xTb[c * NB + tid];          // coalesced dword
        float2 xs = xisf[c];                   // broadcast b64
        float r = xs.x - xj;
        float pp = (r + 2.2f) * 2.5f;
        float fd = floorf(pp);
        int d = (int)fd;
        float u = pp - fd;
        if ((unsigned)d > 10u) d = 11;
        float4 cf = cpad[c][d];                // b128 gather, <=2-way conflict
        e += cf.x + u * (cf.y + u * (cf.z + u * cf.w)) + silu(r) * xs.y;
    }
    if (adj[(b * NB + i) * NB + tid] == 0) e = -1e9f;

    // ---- softmax over j ----
    float mx = e;
#pragma unroll
    for (int off = 32; off > 0; off >>= 1)
        mx = fmaxf(mx, __shfl_xor(mx, off, 64));
    if ((tid & 63) == 0) wred[tid >> 6] = mx;
    __syncthreads();
    mx = fmaxf(fmaxf(wred[0], wred[1]), fmaxf(wred[2], wred[3]));
    float pexp = __expf(e - mx);
    float sw = pexp;
#pragma unroll
    for (int off = 32; off > 0; off >>= 1)
        sw += __shfl_xor(sw, off, 64);
    __syncthreads();
    if ((tid & 63) == 0) wred[tid >> 6] = sw;
    __syncthreads();
    float denom = wred[0] + wred[1] + wred[2] + wred[3];
    alpha[tid] = pexp * __builtin_amdgcn_rcpf(denom);
    __syncthreads();

    // ---- aggr[o] = sum_j alpha[j]*msg[b,j,o] ----
    {
        const int o = tid & 63, seg = tid >> 6;
        const float* msgb = msg + (b * NB + seg * 64) * OUTF;
        float a = 0.0f;
#pragma unroll 8
        for (int jj = 0; jj < 64; ++jj)
            a += alpha[seg * 64 + jj] * msgb[jj * OUTF + o];
        part[seg][o] = a;
    }
    __syncthreads();
    if (tid < OUTF)
        comb[CH + tid] = part[0][tid] + part[1][tid] + part[2][tid] + part[3][tid];
    __syncthreads();

    // ---- update-KAN features (128 channels -> 1152 LDS rows) ----
    if (tid < UIN) {
        float v = comb[tid];
#pragma unroll
        for (int g = 0; g < 8; ++g) Fu[tid * 9 + g] = 0.0f;
        Fu[tid * 9 + 8] = silu(v);
        int d; float4 vv; spline4(v, d, vv);
#pragma unroll
        for (int k = 0; k < 4; ++k) {
            int m = d - 3 + k;
            if ((unsigned)m < 8u) Fu[tid * 9 + m] = ((const float*)&vv)[k];
        }
    }
    __syncthreads();

    // ---- update matvec: 4 waves x 72 float4-k iters, coalesced W ----
    {
        const int o = tid & 63, w = tid >> 6;
        const float4* W = (const float4*)w2u;
        const float4* Fv = (const float4*)Fu;
        float acc = 0.0f;
#pragma unroll 4
        for (int k4 = w * 72; k4 < w * 72 + 72; ++k4) {
            float4 f = Fv[k4];
            float4 wt = W[k4 * 64 + o];
            acc += f.x * wt.x + f.y * wt.y + f.z * wt.z + f.w * wt.w;
        }
        part[w][o] = acc;
    }
    __syncthreads();
    if (tid < OUTF)
        out[(b * NB + i) * OUTF + tid] =
            part[0][tid] + part[1][tid] + part[2][tid] + part[3][tid];
}

extern "C" void kernel_launch(void* const* d_in, const int* in_sizes, int n_in,
                              void* d_out, int out_size, void* d_ws, size_t ws_size,
                              hipStream_t stream) {
    const float* x     = (const float*)d_in[0];
    const int*   adj   = (const int*)d_in[1];
    const float* fwb   = (const float*)d_in[2];
    const float* fws   = (const float*)d_in[3];
    const float* fwsc  = (const float*)d_in[4];
    const float* mwb   = (const float*)d_in[5];
    const float* mws   = (const float*)d_in[6];
    const float* mwsc  = (const float*)d_in[7];
    const float* uwb   = (const float*)d_in[8];
    const float* uws   = (const float*)d_in[9];
    const float* uwsc  = (const float*)d_in[10];
    float* out = (float*)d_out;
    float* ws = (float*)d_ws;

    const int BN = in_sizes[0] / CH;   // 512

    const int prep_threads = 2 * NB * CH + KM4 * OUTF + KU4 * OUTF; // 60416
    prep_kernel<<<(prep_threads + 255) / 256, 256, 0, stream>>>(
        x, mwb, mws, mwsc, uwb, uws, uwsc, ws);
    msg_kernel<<<BN, 256, 0, stream>>>(x, ws + WS_W2M, ws + WS_MSG);
    gat_kernel<<<BN, 256, 0, stream>>>(ws + WS_XT, x, adj, fwb, fws, fwsc,
                                       ws + WS_W2U, ws + WS_MSG, out);
}